// Round 4
// baseline (836.409 us; speedup 1.0000x reference)
//
#include <hip/hip_runtime.h>
#include <hip/hip_bf16.h>
#include <math.h>

// 256x256x64 8-wave GEMM core: staggered half-tile pipeline, counted vmcnt
// (6/6/4), 3 barriers/tile, chunk-major conflict-free LDS, int-offset LDS
// addressing, increment-only global staging pointers, no setprio.
#define BM 256
#define BN 256
#define BK 64

typedef __bf16 bf16x8_t __attribute__((ext_vector_type(8)));
typedef __bf16 bf16x4_t __attribute__((ext_vector_type(4)));
typedef float f32x16_t __attribute__((ext_vector_type(16)));

static __device__ __forceinline__ float bf2f(__bf16 b) {
    unsigned short s = __builtin_bit_cast(unsigned short, b);
    unsigned int u = ((unsigned int)s) << 16;
    return __builtin_bit_cast(float, u);
}
static __device__ __forceinline__ __bf16 f2bf(float f) {
    unsigned int u = __builtin_bit_cast(unsigned int, f);
    unsigned int r = (u + 0x7fffu + ((u >> 16) & 1u)) >> 16;
    return __builtin_bit_cast(__bf16, (unsigned short)r);
}
// GELU tanh-form, |err vs exact| ~1e-3 << 4e-2 tolerance.
static __device__ __forceinline__ float gelu_fast(float x) {
    const float s = x * (0.7978845608f + 0.0356774081f * x * x);
    const float e = __expf(-2.0f * s);
    return x * __builtin_amdgcn_rcpf(1.0f + e);
}

#define GLDS16(gp, lp)                                                                   \
    __builtin_amdgcn_global_load_lds((const __attribute__((address_space(1))) void*)(gp), \
                                     (__attribute__((address_space(3))) void*)(lp), 16, 0, 0)

// ---------------------------------------------------------------------------
// frag_cast: fp32 W[K][N] -> bf16 B'[K/8][N][8], B'[c][n][j] = W[c*8+j][n].
// ---------------------------------------------------------------------------
__global__ __launch_bounds__(256) void frag_cast(const float* __restrict__ in,
                                                 __bf16* __restrict__ out,
                                                 int K, int N,
                                                 size_t inStride, size_t outStride) {
    in += (size_t)blockIdx.z * inStride;
    out += (size_t)blockIdx.z * outStride;
    __shared__ float tile[64][65];
    const int k0 = blockIdx.x * 64, n0 = blockIdx.y * 64;
    const int tid = threadIdx.x;
    const int r = tid >> 4, c4 = (tid & 15) * 4;
#pragma unroll
    for (int p = 0; p < 4; ++p) {
        const float4 v = *(const float4*)&in[(size_t)(k0 + r + p * 16) * N + n0 + c4];
        tile[r + p * 16][c4 + 0] = v.x;
        tile[r + p * 16][c4 + 1] = v.y;
        tile[r + p * 16][c4 + 2] = v.z;
        tile[r + p * 16][c4 + 3] = v.w;
    }
    __syncthreads();
    const int c = tid >> 5, nn0 = (tid & 31) * 2;
#pragma unroll
    for (int t = 0; t < 2; ++t) {
        const int nn = nn0 + t;
        bf16x8_t v;
#pragma unroll
        for (int j = 0; j < 8; ++j) v[j] = f2bf(tile[c * 8 + j][nn]);
        *(bf16x8_t*)&out[((size_t)(k0 >> 3) + c) * N * 8 + (size_t)(n0 + nn) * 8] = v;
    }
}

// ---------------------------------------------------------------------------
// Cast two equal-size fp32 tensors to one contiguous bf16 buffer.
// ---------------------------------------------------------------------------
__global__ __launch_bounds__(256) void cast2_kernel(const float* __restrict__ a,
                                                    const float* __restrict__ b,
                                                    __bf16* __restrict__ out, int n8each) {
    const int i = blockIdx.x * 256 + threadIdx.x;
    if (i < 2 * n8each) {
        const float* src = (i < n8each) ? a : b;
        const size_t idx = (i < n8each) ? (size_t)i : (size_t)(i - n8each);
        const float4* p = (const float4*)(src + idx * 8);
        const float4 x = p[0], y = p[1];
        bf16x8_t v;
        v[0] = f2bf(x.x); v[1] = f2bf(x.y); v[2] = f2bf(x.z); v[3] = f2bf(x.w);
        v[4] = f2bf(y.x); v[5] = f2bf(y.y); v[6] = f2bf(y.z); v[7] = f2bf(y.w);
        *(bf16x8_t*)(out + (size_t)i * 8) = v;
    }
}

// ---------------------------------------------------------------------------
// cast_acat: visual[8192][768] + text[8192][768] fp32 -> acat[8192][1536] bf16
// ---------------------------------------------------------------------------
__global__ __launch_bounds__(256) void cast_acat(const float* __restrict__ vis,
                                                 const float* __restrict__ txt,
                                                 __bf16* __restrict__ out, int total8) {
    const int i = blockIdx.x * 256 + threadIdx.x;
    if (i < total8) {
        const int r = i / 192;           // 1536/8 chunks per row
        const int c8 = i - r * 192;
        const float* src = (c8 < 96) ? vis + (size_t)r * 768 + (size_t)c8 * 8
                                     : txt + (size_t)r * 768 + (size_t)(c8 - 96) * 8;
        const float4* p = (const float4*)src;
        const float4 x = p[0], y = p[1];
        bf16x8_t v;
        v[0] = f2bf(x.x); v[1] = f2bf(x.y); v[2] = f2bf(x.z); v[3] = f2bf(x.w);
        v[4] = f2bf(y.x); v[5] = f2bf(y.y); v[6] = f2bf(y.z); v[7] = f2bf(y.w);
        *(bf16x8_t*)(out + (size_t)i * 8) = v;
    }
}

#define MFMA32(a, b, c) __builtin_amdgcn_mfma_f32_32x32x16_bf16(a, b, c, 0, 0, 0)

// ---------------------------------------------------------------------------
// Core: 256x256x64 tile, 512 threads = 8 waves (2M x 4N), per-wave output
// 128x64: rows wm*64 + (mi&1)*32 + (mi>>1)*128, cols wn*32 + ni*128.
//
// LDS 128 KiB: per tensor [buf(2)][half(2)][chunk(8)][row(128)][8] (16 KB
// half-slots). All ds_read_b128 lane-contiguous (0 bank conflicts, R1 PMC).
//
// Phases per tile (halves staged one/phase, consumed >=2 phases later):
//   p0: stage A0,B0(kt+1); read A0,B0(kt); MFMA acc[0..1][0]; vmcnt(6); bar
//   p1: stage A1(kt+1);    read A1(kt);    MFMA acc[2..3][0]; vmcnt(6); bar
//   p2: stage B1(kt+1);    read B1(kt);    MFMA acc[2..3][1] (A1 in regs)
//   p3:                    re-read A0(kt); MFMA acc[0..1][1]; vmcnt(4); bar
// sched_barrier(0) ONLY at {before vmcnt, after s_barrier}: GLDS counts stay
// exact, and within a phase reads/MFMA/stage interleave freely (compiler's
// partial-lgkmcnt pipelining). No setprio (it fenced read/MFMA overlap, R2).
// All LDS addressing is int-offset with literal adders (ds offset folding);
// global staging pointers advance by += (no per-phase remultiplication).
// ---------------------------------------------------------------------------
template <int ACT, int PACK>
static __device__ __forceinline__ void gemm_core(const __bf16* __restrict__ A, int lda,
                                                 const __bf16* __restrict__ Bt, int Bn,
                                                 const float* __restrict__ bias,
                                                 __bf16* __restrict__ C, int ldc, int K,
                                                 int bm, int bn,
                                                 __bf16* As, __bf16* Bs) {
    const int tid = threadIdx.x;
    const int lane = tid & 63, wave = tid >> 6;
    const int wm = wave >> 2, wn = wave & 3;
    const int l = lane & 31, hi = lane >> 5;

    const size_t Bn8 = (size_t)Bn * 8;
    const int HSZ = 8192;                    // elems per half-slot (16 KB)

    // global staging pointers: [cg][h] cg=chunk-group(0..3 / 4..7), h=M/N half
    const int rr = tid & 127;
    const int cg = tid >> 7;                 // 0..3
    const __bf16* aP[4];
    const __bf16* bP[4];
    aP[0] = A + (size_t)(bm * BM + rr) * lda + cg * 8;
    aP[1] = aP[0] + 32;                      // +4 chunks
    aP[2] = aP[0] + (size_t)128 * lda;       // half 1 rows
    aP[3] = aP[1] + (size_t)128 * lda;
    bP[0] = Bt + (size_t)cg * Bn8 + (size_t)(bn * BN + rr) * 8;
    bP[1] = bP[0] + 4 * Bn8;
    bP[2] = bP[0] + (size_t)128 * 8;         // half 1 cols
    bP[3] = bP[1] + (size_t)128 * 8;
    const size_t bAdv = 8 * Bn8;             // B advance per K-tile

    // LDS frag-read base offsets (elements, int): chunk(2s+hi), row, half
    const int aBase = (wm * 64 + l) * 8 + hi * 1024;
    const int bBase = (wn * 32 + l) * 8 + hi * 1024;
    const int dBase = tid * 8;               // staging dest base within buffer

    f32x16_t acc[4][2] = {};

    // prologue: stage tile 0 into buffer 0 (A0,B0,A1,B1 = steady issue order)
    GLDS16(aP[0], As + dBase); GLDS16(aP[1], As + dBase + 4096);
    GLDS16(bP[0], Bs + dBase); GLDS16(bP[1], Bs + dBase + 4096);
    GLDS16(aP[2], As + dBase + HSZ); GLDS16(aP[3], As + dBase + HSZ + 4096);
    GLDS16(bP[2], Bs + dBase + HSZ); GLDS16(bP[3], Bs + dBase + HSZ + 4096);
    __builtin_amdgcn_sched_barrier(0);
    asm volatile("s_waitcnt vmcnt(4)");      // A0,B0 landed; A1,B1 in flight
    __builtin_amdgcn_s_barrier();
    __builtin_amdgcn_sched_barrier(0);

    const int nk = K / BK;
    // advance staging pointers to tile 1
    if (nk > 1) {
#pragma unroll
        for (int i = 0; i < 4; ++i) { aP[i] += BK; bP[i] += bAdv; }
    }

    int rdO = 0, dstO = 2 * HSZ;
    for (int kt = 0; kt < nk; ++kt) {
        bf16x8_t af[4][2], bfr[4];
        const int aO = aBase + rdO, bO = bBase + rdO;
        const int dA = dBase + dstO, dB = dBase + dstO;

        // ---- p0: stage A0,B0(next); (A0,B0) -> acc[0..1][0]
        GLDS16(aP[0], As + dA); GLDS16(aP[1], As + dA + 4096);
        GLDS16(bP[0], Bs + dB); GLDS16(bP[1], Bs + dB + 4096);
#pragma unroll
        for (int s = 0; s < 4; ++s) {
            af[s][0] = *(const bf16x8_t*)(As + aO + s * 2048);
            af[s][1] = *(const bf16x8_t*)(As + aO + s * 2048 + 256);
            bfr[s]   = *(const bf16x8_t*)(Bs + bO + s * 2048);
        }
#pragma unroll
        for (int s = 0; s < 4; ++s) {
            acc[0][0] = MFMA32(af[s][0], bfr[s], acc[0][0]);
            acc[1][0] = MFMA32(af[s][1], bfr[s], acc[1][0]);
        }
        __builtin_amdgcn_sched_barrier(0);
        asm volatile("s_waitcnt vmcnt(6)");  // A1(kt) landed
        __builtin_amdgcn_s_barrier();
        __builtin_amdgcn_sched_barrier(0);

        // ---- p1: stage A1(next); (A1,B0) -> acc[2..3][0]
        GLDS16(aP[2], As + dA + HSZ); GLDS16(aP[3], As + dA + HSZ + 4096);
#pragma unroll
        for (int s = 0; s < 4; ++s) {
            af[s][0] = *(const bf16x8_t*)(As + aO + HSZ + s * 2048);
            af[s][1] = *(const bf16x8_t*)(As + aO + HSZ + s * 2048 + 256);
        }
#pragma unroll
        for (int s = 0; s < 4; ++s) {
            acc[2][0] = MFMA32(af[s][0], bfr[s], acc[2][0]);
            acc[3][0] = MFMA32(af[s][1], bfr[s], acc[3][0]);
        }
        __builtin_amdgcn_sched_barrier(0);
        asm volatile("s_waitcnt vmcnt(6)");  // B1(kt) landed
        __builtin_amdgcn_s_barrier();
        __builtin_amdgcn_sched_barrier(0);

        // ---- p2: stage B1(next); (A1,B1) -> acc[2..3][1]  (A1 in regs)
        GLDS16(bP[2], Bs + dB + HSZ); GLDS16(bP[3], Bs + dB + HSZ + 4096);
#pragma unroll
        for (int s = 0; s < 4; ++s) bfr[s] = *(const bf16x8_t*)(Bs + bO + HSZ + s * 2048);
#pragma unroll
        for (int s = 0; s < 4; ++s) {
            acc[2][1] = MFMA32(af[s][0], bfr[s], acc[2][1]);
            acc[3][1] = MFMA32(af[s][1], bfr[s], acc[3][1]);
        }
        // ---- p3 (no barrier): (A0 re-read,B1) -> acc[0..1][1]
#pragma unroll
        for (int s = 0; s < 4; ++s) {
            af[s][0] = *(const bf16x8_t*)(As + aO + s * 2048);
            af[s][1] = *(const bf16x8_t*)(As + aO + s * 2048 + 256);
        }
#pragma unroll
        for (int s = 0; s < 4; ++s) {
            acc[0][1] = MFMA32(af[s][0], bfr[s], acc[0][1]);
            acc[1][1] = MFMA32(af[s][1], bfr[s], acc[1][1]);
        }
        __builtin_amdgcn_sched_barrier(0);
        asm volatile("s_waitcnt vmcnt(4)");  // A0,B0(kt+1) landed
        __builtin_amdgcn_s_barrier();
        __builtin_amdgcn_sched_barrier(0);

        rdO ^= 2 * HSZ; dstO ^= 2 * HSZ;
        if (kt + 2 < nk) {
#pragma unroll
            for (int i = 0; i < 4; ++i) { aP[i] += BK; bP[i] += bAdv; }
        }
    }

    // epilogue: 32x32 C/D layout: col = lane&31, row = (reg&3)+8*(reg>>2)+4*hi
    const int colb = bn * BN + wn * 32 + l;
    const int rowb = bm * BM + wm * 64 + 4 * hi;
#pragma unroll
    for (int ni = 0; ni < 2; ++ni) {
        const int col = colb + ni * 128;
        const float bv = PACK ? 0.0f : bias[col];
#pragma unroll
        for (int mi = 0; mi < 4; ++mi) {
            const int row0 = rowb + (mi >> 1) * 128 + (mi & 1) * 32;
#pragma unroll
            for (int v = 0; v < 16; ++v) {
                const int row = row0 + (v & 3) + 8 * (v >> 2);
                float x = acc[mi][ni][v] + bv;
                if (ACT == 1) x = gelu_fast(x);
                if (PACK) {
                    C[((size_t)(row >> 3)) * (size_t)ldc * 8 + (size_t)col * 8 + (row & 7)] = f2bf(x);
                } else {
                    C[(size_t)row * ldc + col] = f2bf(x);
                }
            }
        }
    }
}

template <int ACT>
__global__ __launch_bounds__(512, 2) void gemm_bt(const __bf16* __restrict__ Ab, int lda, size_t strideAe,
                                                  const __bf16* __restrict__ Bb, int Bn, size_t strideBe,
                                                  const float* __restrict__ biasb, size_t strideBiasE,
                                                  __bf16* __restrict__ Cb, int ldc, size_t strideCe,
                                                  int K) {
    __shared__ __bf16 As[2 * 2 * 8192];  // 64 KB
    __shared__ __bf16 Bs[2 * 2 * 8192];  // 64 KB
    gemm_core<ACT, 0>(Ab + (size_t)blockIdx.z * strideAe, lda,
                      Bb + (size_t)blockIdx.z * strideBe, Bn,
                      biasb + (size_t)blockIdx.z * strideBiasE,
                      Cb + (size_t)blockIdx.z * strideCe, ldc, K,
                      blockIdx.x, blockIdx.y, As, Bs);
}

// Weight pre-multiply: W1cat[e] rows [0,768) = vis_w@w1_top[e], rows [768,1536)
// = txt_w@w1_bot[e]; output written frag-packed for direct use as B in w1 GEMM.
__global__ __launch_bounds__(512, 2) void gemm_premul(const __bf16* __restrict__ wbf,
                                                      const __bf16* __restrict__ w1t,
                                                      __bf16* __restrict__ w1cat) {
    __shared__ __bf16 As[2 * 2 * 8192];
    __shared__ __bf16 Bs[2 * 2 * 8192];
    const int e = blockIdx.z & 7, hf = blockIdx.z >> 3;
    gemm_core<0, 1>(wbf + (size_t)hf * 768 * 1024, 1024,
                    w1t + (size_t)e * 2048 * 1024 + (size_t)hf * 128 * 1024 * 8, 1024,
                    nullptr,
                    w1cat + (size_t)e * 1536 * 1024 + (size_t)hf * 96 * 1024 * 8, 1024, 1024,
                    blockIdx.x, blockIdx.y, As, Bs);
}

// ---------------------------------------------------------------------------
// b1t[e][n] = b1[e][n] + sum_d bcat[d]*w1[e][d][n], bcat=[vis_b|txt_b].
// ---------------------------------------------------------------------------
__global__ __launch_bounds__(256) void bias1_kernel(const float* __restrict__ w1,
                                                    const float* __restrict__ vis_b,
                                                    const float* __restrict__ txt_b,
                                                    const float* __restrict__ b1,
                                                    float* __restrict__ b1t) {
    const int n = blockIdx.x * 256 + threadIdx.x;
    const int e = blockIdx.y;
    const int d0 = blockIdx.z * 512;
    float acc = (blockIdx.z == 0) ? b1[(size_t)e * 1024 + n] : 0.0f;
#pragma unroll 4
    for (int d = d0; d < d0 + 512; ++d) {
        const float bv = (d < 1024) ? vis_b[d] : txt_b[d - 1024];
        acc += bv * w1[((size_t)e * 2048 + d) * 1024 + n];
    }
    atomicAdd(&b1t[(size_t)e * 1024 + n], acc);
}

// ---------------------------------------------------------------------------
// Gcat[v][j] (v<1536) = sum_d w_row[v][d]*gw[dglob][j]; block 1536 computes
// bg~[j] = sum_d bcat[d]*gw[d][j] + gate_b[j], stored at Gcat+1536*8.
// ---------------------------------------------------------------------------
__global__ __launch_bounds__(256) void gcat_kernel(const float* __restrict__ vis_w,
                                                   const float* __restrict__ txt_w,
                                                   const float* __restrict__ vis_b,
                                                   const float* __restrict__ txt_b,
                                                   const float* __restrict__ gw,
                                                   const float* __restrict__ gb,
                                                   float* __restrict__ gcat) {
    const int v = blockIdx.x, tid = threadIdx.x;
    const int lane = tid & 63, wv = tid >> 6;
    float a[8] = {0, 0, 0, 0, 0, 0, 0, 0};
    if (v < 1536) {
        const float* wr = (v < 768) ? vis_w + (size_t)v * 1024 : txt_w + (size_t)(v - 768) * 1024;
        const int dbase = (v < 768) ? 0 : 1024;
        for (int d = tid; d < 1024; d += 256) {
            const float c = wr[d];
            const float4* g4 = (const float4*)(gw + (size_t)(dbase + d) * 8);
            const float4 x = g4[0], y = g4[1];
            a[0] += c * x.x; a[1] += c * x.y; a[2] += c * x.z; a[3] += c * x.w;
            a[4] += c * y.x; a[5] += c * y.y; a[6] += c * y.z; a[7] += c * y.w;
        }
    } else {
        for (int d = tid; d < 2048; d += 256) {
            const float c = (d < 1024) ? vis_b[d] : txt_b[d - 1024];
            const float4* g4 = (const float4*)(gw + (size_t)d * 8);
            const float4 x = g4[0], y = g4[1];
            a[0] += c * x.x; a[1] += c * x.y; a[2] += c * x.z; a[3] += c * x.w;
            a[4] += c * y.x; a[5] += c * y.y; a[6] += c * y.z; a[7] += c * y.w;
        }
    }
#pragma unroll
    for (int j = 0; j < 8; ++j)
        for (int off = 32; off; off >>= 1) a[j] += __shfl_down(a[j], off, 64);
    __shared__ float red[4][8];
    if (lane == 0) {
#pragma unroll
        for (int j = 0; j < 8; ++j) red[wv][j] = a[j];
    }
    __syncthreads();
    if (tid < 8) {
        float s = red[0][tid] + red[1][tid] + red[2][tid] + red[3][tid];
        if (v == 1536) s += gb[tid];
        gcat[(size_t)v * 8 + tid] = s;
    }
}

// ---------------------------------------------------------------------------
// Gate: softmax(acat @ Gcat + bg~) over E=8. One block per row.
// ---------------------------------------------------------------------------
__global__ __launch_bounds__(256) void gate_kernel(const __bf16* __restrict__ acat,
                                                   const float* __restrict__ gcat,
                                                   float* __restrict__ gate) {
    const int b = blockIdx.x, tid = threadIdx.x;
    const int lane = tid & 63, wv = tid >> 6;
    const __bf16* row = acat + (size_t)b * 1536;
    float a[8] = {0, 0, 0, 0, 0, 0, 0, 0};
    for (int k = tid; k < 1536; k += 256) {
        const float c = bf2f(row[k]);
        const float4* g4 = (const float4*)(gcat + (size_t)k * 8);
        const float4 x = g4[0], y = g4[1];
        a[0] += c * x.x; a[1] += c * x.y; a[2] += c * x.z; a[3] += c * x.w;
        a[4] += c * y.x; a[5] += c * y.y; a[6] += c * y.z; a[7] += c * y.w;
    }
#pragma unroll
    for (int j = 0; j < 8; ++j)
        for (int off = 32; off; off >>= 1) a[j] += __shfl_down(a[j], off, 64);
    __shared__ float red[4][8];
    if (lane == 0) {
#pragma unroll
        for (int j = 0; j < 8; ++j) red[wv][j] = a[j];
    }
    __syncthreads();
    if (tid == 0) {
        const float* bg = gcat + 1536 * 8;
        float l[8];
        float m = -1e30f;
        for (int j = 0; j < 8; ++j) {
            l[j] = red[0][j] + red[1][j] + red[2][j] + red[3][j] + bg[j];
            m = fmaxf(m, l[j]);
        }
        float s = 0.f;
        for (int j = 0; j < 8; ++j) { l[j] = expf(l[j] - m); s += l[j]; }
        const float inv = 1.0f / s;
        for (int j = 0; j < 8; ++j) gate[(size_t)b * 8 + j] = l[j] * inv;
    }
}

// ---------------------------------------------------------------------------
// Fused LayerNorm + gated expert reduction. One block/row.
// ---------------------------------------------------------------------------
__global__ __launch_bounds__(256) void ln_out_kernel(const __bf16* __restrict__ h2,
                                                     const float* __restrict__ gate,
                                                     const float* __restrict__ lng,
                                                     const float* __restrict__ lnb,
                                                     float* __restrict__ out,
                                                     int Eg, int g0, int accum) {
    const int b = blockIdx.x;
    const int tid = threadIdx.x;
    const int lane = tid & 63, wv = tid >> 6;
    const int d0 = tid * 4;
    __shared__ float sS[4], sSS[4];
    float* orow = out + (size_t)b * 1024 + d0;
    float o0, o1, o2, o3;
    if (accum) {
        const float4 p = *(const float4*)orow;
        o0 = p.x; o1 = p.y; o2 = p.z; o3 = p.w;
    } else {
        o0 = o1 = o2 = o3 = 0.f;
    }
    for (int e = 0; e < Eg; ++e) {
        const __bf16* hp = h2 + ((size_t)e * 8192 + b) * 1024 + d0;
        const bf16x4_t hv = *(const bf16x4_t*)hp;
        const float v0 = bf2f(hv[0]), v1 = bf2f(hv[1]), v2 = bf2f(hv[2]), v3 = bf2f(hv[3]);
        float s = v0 + v1 + v2 + v3;
        float ss = v0 * v0 + v1 * v1 + v2 * v2 + v3 * v3;
        for (int off = 32; off; off >>= 1) {
            s += __shfl_down(s, off, 64);
            ss += __shfl_down(ss, off, 64);
        }
        if (lane == 0) { sS[wv] = s; sSS[wv] = ss; }
        __syncthreads();
        const float S = sS[0] + sS[1] + sS[2] + sS[3];
        const float SS = sSS[0] + sSS[1] + sSS[2] + sSS[3];
        __syncthreads();
        const float mu = S * (1.0f / 1024.0f);
        const float var = SS * (1.0f / 1024.0f) - mu * mu;
        const float rstd = rsqrtf(var + 1e-5f);
        const float w = gate[(size_t)b * 8 + g0 + e];
        const float4 gg = *(const float4*)(lng + (size_t)(g0 + e) * 1024 + d0);
        const float4 bb = *(const float4*)(lnb + (size_t)(g0 + e) * 1024 + d0);
        o0 += w * ((v0 - mu) * rstd * gg.x + bb.x);
        o1 += w * ((v1 - mu) * rstd * gg.y + bb.y);
        o2 += w * ((v2 - mu) * rstd * gg.z + bb.z);
        o3 += w * ((v3 - mu) * rstd * gg.w + bb.w);
    }
    *(float4*)orow = make_float4(o0, o1, o2, o3);
}

// ---------------------------------------------------------------------------
extern "C" void kernel_launch(void* const* d_in, const int* in_sizes, int n_in,
                              void* d_out, int out_size, void* d_ws, size_t ws_size,
                              hipStream_t stream) {
    (void)in_sizes; (void)n_in; (void)out_size;
    const float* visual = (const float*)d_in[0];
    const float* text   = (const float*)d_in[1];
    const float* vis_w  = (const float*)d_in[2];
    const float* vis_b  = (const float*)d_in[3];
    const float* txt_w  = (const float*)d_in[4];
    const float* txt_b  = (const float*)d_in[5];
    const float* gate_w = (const float*)d_in[6];
    const float* gate_b = (const float*)d_in[7];
    const float* w1     = (const float*)d_in[8];
    const float* b1     = (const float*)d_in[9];
    const float* w2     = (const float*)d_in[10];
    const float* b2     = (const float*)d_in[11];
    const float* ln_g   = (const float*)d_in[12];
    const float* ln_b   = (const float*)d_in[13];
    float* out = (float*)d_out;

    const size_t B = 8192, DV = 768, D = 1024, G = 2048, E = 8, KC = 1536;

    char* ws = (char*)d_ws;
    size_t o = 0;
    auto alloc = [&](size_t bytes) { size_t r = o; o = (o + bytes + 255) & ~(size_t)255; return r; };
    const size_t off_wbf   = alloc(2 * DV * D * 2);        // vis_w_bf | txt_w_bf
    const size_t off_w1cat = alloc(E * KC * D * 2);        // fused W1, frag-packed
    const size_t off_w2t   = alloc(E * D * D * 2);
    const size_t off_b1t   = alloc(E * D * 4);
    const size_t off_gcat  = alloc((KC * E + E) * 4);
    const size_t off_gate  = alloc(B * E * 4);
    const size_t off_acat  = alloc(B * KC * 2);
    const size_t fixedEnd = o;
    const size_t w1tBytes = E * G * D * 2;  // 33.5 MB, dead after premul

    int Eg = 1;
    {
        const int cand[4] = {8, 4, 2, 1};
        for (int c = 0; c < 4; ++c) {
            size_t h2b = 2 * (size_t)cand[c] * B * D * 2;
            size_t dyn = h2b > w1tBytes ? h2b : w1tBytes;
            if (fixedEnd + dyn <= ws_size || cand[c] == 1) { Eg = cand[c]; break; }
        }
    }

    __bf16* wbf   = (__bf16*)(ws + off_wbf);
    __bf16* w1cat = (__bf16*)(ws + off_w1cat);
    __bf16* w2t   = (__bf16*)(ws + off_w2t);
    float*  b1t   = (float*)(ws + off_b1t);
    float*  gcat  = (float*)(ws + off_gcat);
    float*  gate  = (float*)(ws + off_gate);
    __bf16* acat  = (__bf16*)(ws + off_acat);
    __bf16* w1t   = (__bf16*)(ws + fixedEnd);              // aliased: dead after premul
    __bf16* h1    = (__bf16*)(ws + fixedEnd);              // overwrites w1t in expert loop
    __bf16* h2    = h1 + (size_t)Eg * B * D;

    // 1) casts: weights (vis_w|txt_w row-major bf16) and activations (acat)
    const int nw8 = (int)(DV * D / 8);
    cast2_kernel<<<(2 * nw8 + 255) / 256, 256, 0, stream>>>(vis_w, txt_w, wbf, nw8);
    const int na8 = (int)(B * KC / 8);
    cast_acat<<<(na8 + 255) / 256, 256, 0, stream>>>(visual, text, acat, na8);

    // 2) frag-pack w1 (B input of premul) and w2
    frag_cast<<<dim3(G / 64, D / 64, E), 256, 0, stream>>>(w1, w1t, (int)G, (int)D, G * D, G * D);
    frag_cast<<<dim3(D / 64, D / 64, E), 256, 0, stream>>>(w2, w2t, (int)D, (int)D, D * D, D * D);

    // 3) weight pre-multiply: W1cat = [vis_w@w1_top ; txt_w@w1_bot], packed
    gemm_premul<<<dim3(768 / BM, D / BN, 16), 512, 0, stream>>>(wbf, w1t, w1cat);

    // 4) fused biases: b1t = b1 + bcat@w1 ; Gcat = [vis_w;txt_w]@gw (+bg~)
    hipMemsetAsync(b1t, 0, E * D * 4, stream);
    bias1_kernel<<<dim3(4, 8, 4), 256, 0, stream>>>(w1, vis_b, txt_b, b1, b1t);
    gcat_kernel<<<1537, 256, 0, stream>>>(vis_w, txt_w, vis_b, txt_b, gate_w, gate_b, gcat);

    // 5) gate softmax from acat
    gate_kernel<<<(int)B, 256, 0, stream>>>(acat, gcat, gate);

    // 6) experts in groups of Eg: h1 = gelu(acat@W1cat + b1t); h2 = h1@w2 + b2; LN+reduce
    const int ng = 8 / Eg;
    for (int g = 0; g < ng; ++g) {
        const int g0 = g * Eg;
        gemm_bt<1><<<dim3(B / BM, D / BN, Eg), 512, 0, stream>>>(
            acat, (int)KC, 0, w1cat + (size_t)g0 * KC * D, (int)D, KC * D,
            b1t + (size_t)g0 * D, D, h1, (int)D, B * D, (int)KC);
        gemm_bt<0><<<dim3(B / BM, D / BN, Eg), 512, 0, stream>>>(
            h1, (int)D, B * D, w2t + (size_t)g0 * D * D, (int)D, D * D,
            b2 + (size_t)g0 * D, D, h2, (int)D, B * D, (int)D);
        ln_out_kernel<<<(int)B, 256, 0, stream>>>(h2, gate, ln_g, ln_b, out, Eg, g0, g > 0 ? 1 : 0);
    }
}

// Round 5
// 825.657 us; speedup vs baseline: 1.0130x; 1.0130x over previous
//
#include <hip/hip_runtime.h>
#include <hip/hip_bf16.h>
#include <math.h>

// Round-0 proven 128x128x64 2-barrier GEMM structure, with A pre-packed in
// tile-packed layout [mblk][chunk][row][8] so that:
//  - global_load_lds staging is fully linear/coalesced (1KB/wave/instr)
//  - LDS frag reads are lane-contiguous -> 0 bank conflicts (round-0 had a
//    forced 4-way conflict: bank=f(chunk) only, 32 lanes over 8 chunks)
//  - staging address VALU collapses to one += per K-tile.
// NOTE: explicit double-buffer/8-phase schedules REGRESSED 3x (R1/R2/R4:
// 180/156/160us vs this structure's 139us) — multi-block/CU overlap beats
// lockstep pipelining here. Do not re-add.
#define BM 128
#define BN 128
#define BK 64

typedef __bf16 bf16x8_t __attribute__((ext_vector_type(8)));
typedef __bf16 bf16x4_t __attribute__((ext_vector_type(4)));
typedef float f32x16_t __attribute__((ext_vector_type(16)));

static __device__ __forceinline__ float bf2f(__bf16 b) {
    unsigned short s = __builtin_bit_cast(unsigned short, b);
    unsigned int u = ((unsigned int)s) << 16;
    return __builtin_bit_cast(float, u);
}
static __device__ __forceinline__ __bf16 f2bf(float f) {
    unsigned int u = __builtin_bit_cast(unsigned int, f);
    unsigned int r = (u + 0x7fffu + ((u >> 16) & 1u)) >> 16;
    return __builtin_bit_cast(__bf16, (unsigned short)r);
}
// GELU tanh-form, |err vs exact| ~1e-3 << 4e-2 tolerance.
static __device__ __forceinline__ float gelu_fast(float x) {
    const float s = x * (0.7978845608f + 0.0356774081f * x * x);
    const float e = __expf(-2.0f * s);
    return x * __builtin_amdgcn_rcpf(1.0f + e);
}

#define GLDS16(gp, lp)                                                                   \
    __builtin_amdgcn_global_load_lds((const __attribute__((address_space(1))) void*)(gp), \
                                     (__attribute__((address_space(3))) void*)(lp), 16, 0, 0)

// ---------------------------------------------------------------------------
// frag_cast: fp32 W[K][N] -> bf16 B'[K/8][N][8], B'[c][n][j] = W[c*8+j][n].
// ---------------------------------------------------------------------------
__global__ __launch_bounds__(256) void frag_cast(const float* __restrict__ in,
                                                 __bf16* __restrict__ out,
                                                 int K, int N,
                                                 size_t inStride, size_t outStride) {
    in += (size_t)blockIdx.z * inStride;
    out += (size_t)blockIdx.z * outStride;
    __shared__ float tile[64][65];
    const int k0 = blockIdx.x * 64, n0 = blockIdx.y * 64;
    const int tid = threadIdx.x;
    const int r = tid >> 4, c4 = (tid & 15) * 4;
#pragma unroll
    for (int p = 0; p < 4; ++p) {
        const float4 v = *(const float4*)&in[(size_t)(k0 + r + p * 16) * N + n0 + c4];
        tile[r + p * 16][c4 + 0] = v.x;
        tile[r + p * 16][c4 + 1] = v.y;
        tile[r + p * 16][c4 + 2] = v.z;
        tile[r + p * 16][c4 + 3] = v.w;
    }
    __syncthreads();
    const int c = tid >> 5, nn0 = (tid & 31) * 2;
#pragma unroll
    for (int t = 0; t < 2; ++t) {
        const int nn = nn0 + t;
        bf16x8_t v;
#pragma unroll
        for (int j = 0; j < 8; ++j) v[j] = f2bf(tile[c * 8 + j][nn]);
        *(bf16x8_t*)&out[((size_t)(k0 >> 3) + c) * N * 8 + (size_t)(n0 + nn) * 8] = v;
    }
}

// ---------------------------------------------------------------------------
// cast2: two fp32 [768][1024] matrices -> bf16 A-packed layout per matrix:
// out[m][mblk][chunk(128)][row(128)][8], chunk = col>>3, row = r&127.
// ---------------------------------------------------------------------------
__global__ __launch_bounds__(256) void cast2_kernel(const float* __restrict__ a,
                                                    const float* __restrict__ b,
                                                    __bf16* __restrict__ out, int n8each) {
    const int i = blockIdx.x * 256 + threadIdx.x;
    if (i < 2 * n8each) {
        const int m = (i < n8each) ? 0 : 1;
        const int ii = i - m * n8each;
        const float* src = (m ? b : a) + (size_t)ii * 8;   // row-major linear
        const int r = ii >> 7, c8 = ii & 127;              // N=1024 -> 128 chunks
        const size_t dst = (size_t)m * 786432 + (size_t)(r >> 7) * 131072 +
                           (size_t)c8 * 1024 + (size_t)(r & 127) * 8;
        const float4* p = (const float4*)src;
        const float4 x = p[0], y = p[1];
        bf16x8_t v;
        v[0] = f2bf(x.x); v[1] = f2bf(x.y); v[2] = f2bf(x.z); v[3] = f2bf(x.w);
        v[4] = f2bf(y.x); v[5] = f2bf(y.y); v[6] = f2bf(y.z); v[7] = f2bf(y.w);
        *(bf16x8_t*)(out + dst) = v;
    }
}

// ---------------------------------------------------------------------------
// cast_acat: visual[8192][768] + text[8192][768] fp32 -> A-packed bf16
// acatP[mblk(64)][chunk(192)][row(128)][8]; logical row = [vis | txt].
// ---------------------------------------------------------------------------
__global__ __launch_bounds__(256) void cast_acat(const float* __restrict__ vis,
                                                 const float* __restrict__ txt,
                                                 __bf16* __restrict__ out, int total8) {
    const int i = blockIdx.x * 256 + threadIdx.x;
    if (i < total8) {
        const int r = i / 192;           // 1536/8 chunks per row
        const int c8 = i - r * 192;
        const float* src = (c8 < 96) ? vis + (size_t)r * 768 + (size_t)c8 * 8
                                     : txt + (size_t)r * 768 + (size_t)(c8 - 96) * 8;
        const float4* p = (const float4*)src;
        const float4 x = p[0], y = p[1];
        bf16x8_t v;
        v[0] = f2bf(x.x); v[1] = f2bf(x.y); v[2] = f2bf(x.z); v[3] = f2bf(x.w);
        v[4] = f2bf(y.x); v[5] = f2bf(y.y); v[6] = f2bf(y.z); v[7] = f2bf(y.w);
        const size_t dst = (size_t)(r >> 7) * 196608 + (size_t)c8 * 1024 +
                           (size_t)(r & 127) * 8;
        *(bf16x8_t*)(out + dst) = v;
    }
}

#define MFMA32(a, b, c) __builtin_amdgcn_mfma_f32_32x32x16_bf16(a, b, c, 0, 0, 0)

// ---------------------------------------------------------------------------
// Core bf16 GEMM tile (round-0 schedule): C[128x128] = act(A @ W + bias).
// A in packed layout [mblk][K/8 chunks][128 rows][8]; W frag-packed
// B'[K/8][N][8] read straight to VGPRs. 2x2 waves x (2x2 mfma 32x32x16).
// PACK: 0 = row-major C; 1 = B-frag-packed C [M/8][N][8] (premul output);
//       2 = A-packed C [mblk][chunk][row][8] (feeds next GEMM's A).
// ---------------------------------------------------------------------------
template <int ACT, int PACK>
static __device__ __forceinline__ void gemm_core(const __bf16* __restrict__ A, int K,
                                                 const __bf16* __restrict__ Bt, int Bn,
                                                 const float* __restrict__ bias,
                                                 __bf16* __restrict__ C, int ldc,
                                                 int bm, int bn, __bf16* As) {
    const int tid = threadIdx.x;
    const int lane = tid & 63, wave = tid >> 6;
    const int wm = wave >> 1, wn = wave & 1;
    const int l = lane & 31, hi = lane >> 5;

    // A staging: packed source is linear -> coalesced 1KB/wave, linear dest.
    const __bf16* ag = A + (size_t)bm * K * 128 + (size_t)tid * 8;
    __bf16* asl = As + tid * 8;

    // A frag read: chunk (2s+hi)*1024 + (row wm*64 + mi*32 + l)*8; lane-contig.
    const __bf16* base_a = As + hi * 1024 + (wm * 64 + l) * 8;

    // B fragment base: frag(s,ni) at chunk kt*8+2s+hi, col bn*BN+wn*64+ni*32+l
    const size_t Bn8 = (size_t)Bn * 8;
    const __bf16* bbase = Bt + (size_t)hi * Bn8 + (size_t)(bn * BN + wn * 64 + l) * 8;
    const size_t bAdv = 8 * Bn8;

    f32x16_t acc[2][2] = {};

    const int nk = K / BK;
    for (int kt = 0; kt < nk; ++kt) {
        bf16x8_t bfr[4][2];
#pragma unroll
        for (int s = 0; s < 4; ++s) {
            bfr[s][0] = *(const bf16x8_t*)(bbase + (size_t)(2 * s) * Bn8);
            bfr[s][1] = *(const bf16x8_t*)(bbase + (size_t)(2 * s) * Bn8 + 256);
        }
        GLDS16(ag, asl);
        GLDS16(ag + 2048, asl + 2048);
        GLDS16(ag + 4096, asl + 4096);
        GLDS16(ag + 6144, asl + 6144);
        ag += 8192;
        bbase += bAdv;
        __syncthreads();
#pragma unroll
        for (int s = 0; s < 4; ++s) {
            const bf16x8_t a0 = *(const bf16x8_t*)(base_a + s * 2048);
            const bf16x8_t a1 = *(const bf16x8_t*)(base_a + s * 2048 + 256);
            acc[0][0] = MFMA32(a0, bfr[s][0], acc[0][0]);
            acc[0][1] = MFMA32(a0, bfr[s][1], acc[0][1]);
            acc[1][0] = MFMA32(a1, bfr[s][0], acc[1][0]);
            acc[1][1] = MFMA32(a1, bfr[s][1], acc[1][1]);
        }
        __syncthreads();
    }

    // epilogue: 32x32 C/D layout: col = lane&31, row = (reg&3)+8*(reg>>2)+4*hi
    const int colbase = bn * BN + wn * 64 + l;
    const int rowbase = bm * BM + wm * 64 + 4 * hi;
#pragma unroll
    for (int ni = 0; ni < 2; ++ni) {
        const int col = colbase + ni * 32;
        const float bv = (PACK == 1) ? 0.0f : bias[col];
#pragma unroll
        for (int mi = 0; mi < 2; ++mi) {
#pragma unroll
            for (int v = 0; v < 16; ++v) {
                const int row = rowbase + mi * 32 + (v & 3) + 8 * (v >> 2);
                float x = acc[mi][ni][v] + bv;
                if (ACT == 1) x = gelu_fast(x);
                if (PACK == 1) {
                    C[((size_t)(row >> 3)) * (size_t)ldc * 8 + (size_t)col * 8 + (row & 7)] = f2bf(x);
                } else if (PACK == 2) {
                    C[(size_t)(row >> 7) * (size_t)ldc * 128 + (size_t)(col >> 3) * 1024 +
                      (size_t)(row & 127) * 8 + (col & 7)] = f2bf(x);
                } else {
                    C[(size_t)row * ldc + col] = f2bf(x);
                }
            }
        }
    }
}

template <int ACT, int PACK>
__global__ __launch_bounds__(256) void gemm_bt(const __bf16* __restrict__ Ab, int K, size_t strideAe,
                                               const __bf16* __restrict__ Bb, int Bn, size_t strideBe,
                                               const float* __restrict__ biasb, size_t strideBiasE,
                                               __bf16* __restrict__ Cb, int ldc, size_t strideCe) {
    __shared__ __bf16 As[BM * BK];  // 16 KB
    gemm_core<ACT, PACK>(Ab + (size_t)blockIdx.z * strideAe, K,
                         Bb + (size_t)blockIdx.z * strideBe, Bn,
                         biasb + (size_t)blockIdx.z * strideBiasE,
                         Cb + (size_t)blockIdx.z * strideCe, ldc,
                         blockIdx.x, blockIdx.y, As);
}

// Weight pre-multiply: W1cat[e] rows [0,768) = vis_w@w1_top[e], rows [768,1536)
// = txt_w@w1_bot[e]; output frag-packed for direct use as B in w1 GEMM.
// z = e + 8*hf; M=768, N=1024, K=1024. A = packed wbf (cast2 layout).
__global__ __launch_bounds__(256) void gemm_premul(const __bf16* __restrict__ wbf,
                                                   const __bf16* __restrict__ w1t,
                                                   __bf16* __restrict__ w1cat) {
    __shared__ __bf16 As[BM * BK];
    const int e = blockIdx.z & 7, hf = blockIdx.z >> 3;
    gemm_core<0, 1>(wbf + (size_t)hf * 786432, 1024,
                    w1t + (size_t)e * 2048 * 1024 + (size_t)hf * 128 * 1024 * 8, 1024,
                    nullptr,
                    w1cat + (size_t)e * 1536 * 1024 + (size_t)hf * 96 * 1024 * 8, 1024,
                    blockIdx.x, blockIdx.y, As);
}

// ---------------------------------------------------------------------------
// b1t[e][n] = b1[e][n] + sum_d bcat[d]*w1[e][d][n], bcat=[vis_b|txt_b].
// ---------------------------------------------------------------------------
__global__ __launch_bounds__(256) void bias1_kernel(const float* __restrict__ w1,
                                                    const float* __restrict__ vis_b,
                                                    const float* __restrict__ txt_b,
                                                    const float* __restrict__ b1,
                                                    float* __restrict__ b1t) {
    const int n = blockIdx.x * 256 + threadIdx.x;
    const int e = blockIdx.y;
    const int d0 = blockIdx.z * 512;
    float acc = (blockIdx.z == 0) ? b1[(size_t)e * 1024 + n] : 0.0f;
#pragma unroll 4
    for (int d = d0; d < d0 + 512; ++d) {
        const float bv = (d < 1024) ? vis_b[d] : txt_b[d - 1024];
        acc += bv * w1[((size_t)e * 2048 + d) * 1024 + n];
    }
    atomicAdd(&b1t[(size_t)e * 1024 + n], acc);
}

// ---------------------------------------------------------------------------
// Gcat[v][j] (v<1536) = sum_d w_row[v][d]*gw[dglob][j]; block 1536 computes
// bg~[j] = sum_d bcat[d]*gw[d][j] + gate_b[j], stored at Gcat+1536*8.
// ---------------------------------------------------------------------------
__global__ __launch_bounds__(256) void gcat_kernel(const float* __restrict__ vis_w,
                                                   const float* __restrict__ txt_w,
                                                   const float* __restrict__ vis_b,
                                                   const float* __restrict__ txt_b,
                                                   const float* __restrict__ gw,
                                                   const float* __restrict__ gb,
                                                   float* __restrict__ gcat) {
    const int v = blockIdx.x, tid = threadIdx.x;
    const int lane = tid & 63, wv = tid >> 6;
    float a[8] = {0, 0, 0, 0, 0, 0, 0, 0};
    if (v < 1536) {
        const float* wr = (v < 768) ? vis_w + (size_t)v * 1024 : txt_w + (size_t)(v - 768) * 1024;
        const int dbase = (v < 768) ? 0 : 1024;
        for (int d = tid; d < 1024; d += 256) {
            const float c = wr[d];
            const float4* g4 = (const float4*)(gw + (size_t)(dbase + d) * 8);
            const float4 x = g4[0], y = g4[1];
            a[0] += c * x.x; a[1] += c * x.y; a[2] += c * x.z; a[3] += c * x.w;
            a[4] += c * y.x; a[5] += c * y.y; a[6] += c * y.z; a[7] += c * y.w;
        }
    } else {
        for (int d = tid; d < 2048; d += 256) {
            const float c = (d < 1024) ? vis_b[d] : txt_b[d - 1024];
            const float4* g4 = (const float4*)(gw + (size_t)d * 8);
            const float4 x = g4[0], y = g4[1];
            a[0] += c * x.x; a[1] += c * x.y; a[2] += c * x.z; a[3] += c * x.w;
            a[4] += c * y.x; a[5] += c * y.y; a[6] += c * y.z; a[7] += c * y.w;
        }
    }
#pragma unroll
    for (int j = 0; j < 8; ++j)
        for (int off = 32; off; off >>= 1) a[j] += __shfl_down(a[j], off, 64);
    __shared__ float red[4][8];
    if (lane == 0) {
#pragma unroll
        for (int j = 0; j < 8; ++j) red[wv][j] = a[j];
    }
    __syncthreads();
    if (tid < 8) {
        float s = red[0][tid] + red[1][tid] + red[2][tid] + red[3][tid];
        if (v == 1536) s += gb[tid];
        gcat[(size_t)v * 8 + tid] = s;
    }
}

// ---------------------------------------------------------------------------
// Gate: softmax(acat @ Gcat + bg~) over E=8. One block per row; acat packed:
// row b chunk k8 at acat[(b>>7)*196608 + k8*1024 + (b&127)*8].
// ---------------------------------------------------------------------------
__global__ __launch_bounds__(256) void gate_kernel(const __bf16* __restrict__ acat,
                                                   const float* __restrict__ gcat,
                                                   float* __restrict__ gate) {
    const int b = blockIdx.x, tid = threadIdx.x;
    const int lane = tid & 63, wv = tid >> 6;
    const __bf16* base = acat + (size_t)(b >> 7) * 196608 + (size_t)(b & 127) * 8;
    float a[8] = {0, 0, 0, 0, 0, 0, 0, 0};
    if (tid < 192) {
        const bf16x8_t av = *(const bf16x8_t*)(base + (size_t)tid * 1024);
#pragma unroll
        for (int jj = 0; jj < 8; ++jj) {
            const float c = bf2f(av[jj]);
            const float4* g4 = (const float4*)(gcat + (size_t)(tid * 8 + jj) * 8);
            const float4 x = g4[0], y = g4[1];
            a[0] += c * x.x; a[1] += c * x.y; a[2] += c * x.z; a[3] += c * x.w;
            a[4] += c * y.x; a[5] += c * y.y; a[6] += c * y.z; a[7] += c * y.w;
        }
    }
#pragma unroll
    for (int j = 0; j < 8; ++j)
        for (int off = 32; off; off >>= 1) a[j] += __shfl_down(a[j], off, 64);
    __shared__ float red[4][8];
    if (lane == 0) {
#pragma unroll
        for (int j = 0; j < 8; ++j) red[wv][j] = a[j];
    }
    __syncthreads();
    if (tid == 0) {
        const float* bg = gcat + 1536 * 8;
        float l[8];
        float m = -1e30f;
        for (int j = 0; j < 8; ++j) {
            l[j] = red[0][j] + red[1][j] + red[2][j] + red[3][j] + bg[j];
            m = fmaxf(m, l[j]);
        }
        float s = 0.f;
        for (int j = 0; j < 8; ++j) { l[j] = expf(l[j] - m); s += l[j]; }
        const float inv = 1.0f / s;
        for (int j = 0; j < 8; ++j) gate[(size_t)b * 8 + j] = l[j] * inv;
    }
}

// ---------------------------------------------------------------------------
// Fused LayerNorm + gated expert reduction (h2 row-major). One block/row.
// ---------------------------------------------------------------------------
__global__ __launch_bounds__(256) void ln_out_kernel(const __bf16* __restrict__ h2,
                                                     const float* __restrict__ gate,
                                                     const float* __restrict__ lng,
                                                     const float* __restrict__ lnb,
                                                     float* __restrict__ out,
                                                     int Eg, int g0, int accum) {
    const int b = blockIdx.x;
    const int tid = threadIdx.x;
    const int lane = tid & 63, wv = tid >> 6;
    const int d0 = tid * 4;
    __shared__ float sS[4], sSS[4];
    float* orow = out + (size_t)b * 1024 + d0;
    float o0, o1, o2, o3;
    if (accum) {
        const float4 p = *(const float4*)orow;
        o0 = p.x; o1 = p.y; o2 = p.z; o3 = p.w;
    } else {
        o0 = o1 = o2 = o3 = 0.f;
    }
    for (int e = 0; e < Eg; ++e) {
        const __bf16* hp = h2 + ((size_t)e * 8192 + b) * 1024 + d0;
        const bf16x4_t hv = *(const bf16x4_t*)hp;
        const float v0 = bf2f(hv[0]), v1 = bf2f(hv[1]), v2 = bf2f(hv[2]), v3 = bf2f(hv[3]);
        float s = v0 + v1 + v2 + v3;
        float ss = v0 * v0 + v1 * v1 + v2 * v2 + v3 * v3;
        for (int off = 32; off; off >>= 1) {
            s += __shfl_down(s, off, 64);
            ss += __shfl_down(ss, off, 64);
        }
        if (lane == 0) { sS[wv] = s; sSS[wv] = ss; }
        __syncthreads();
        const float S = sS[0] + sS[1] + sS[2] + sS[3];
        const float SS = sSS[0] + sSS[1] + sSS[2] + sSS[3];
        __syncthreads();
        const float mu = S * (1.0f / 1024.0f);
        const float var = SS * (1.0f / 1024.0f) - mu * mu;
        const float rstd = rsqrtf(var + 1e-5f);
        const float w = gate[(size_t)b * 8 + g0 + e];
        const float4 gg = *(const float4*)(lng + (size_t)(g0 + e) * 1024 + d0);
        const float4 bb = *(const float4*)(lnb + (size_t)(g0 + e) * 1024 + d0);
        o0 += w * ((v0 - mu) * rstd * gg.x + bb.x);
        o1 += w * ((v1 - mu) * rstd * gg.y + bb.y);
        o2 += w * ((v2 - mu) * rstd * gg.z + bb.z);
        o3 += w * ((v3 - mu) * rstd * gg.w + bb.w);
    }
    *(float4*)orow = make_float4(o0, o1, o2, o3);
}

// ---------------------------------------------------------------------------
extern "C" void kernel_launch(void* const* d_in, const int* in_sizes, int n_in,
                              void* d_out, int out_size, void* d_ws, size_t ws_size,
                              hipStream_t stream) {
    (void)in_sizes; (void)n_in; (void)out_size;
    const float* visual = (const float*)d_in[0];
    const float* text   = (const float*)d_in[1];
    const float* vis_w  = (const float*)d_in[2];
    const float* vis_b  = (const float*)d_in[3];
    const float* txt_w  = (const float*)d_in[4];
    const float* txt_b  = (const float*)d_in[5];
    const float* gate_w = (const float*)d_in[6];
    const float* gate_b = (const float*)d_in[7];
    const float* w1     = (const float*)d_in[8];
    const float* b1     = (const float*)d_in[9];
    const float* w2     = (const float*)d_in[10];
    const float* b2     = (const float*)d_in[11];
    const float* ln_g   = (const float*)d_in[12];
    const float* ln_b   = (const float*)d_in[13];
    float* out = (float*)d_out;

    const size_t B = 8192, DV = 768, D = 1024, G = 2048, E = 8, KC = 1536;

    char* ws = (char*)d_ws;
    size_t o = 0;
    auto alloc = [&](size_t bytes) { size_t r = o; o = (o + bytes + 255) & ~(size_t)255; return r; };
    const size_t off_wbf   = alloc(2 * DV * D * 2);        // packed vis_w | txt_w
    const size_t off_w1cat = alloc(E * KC * D * 2);        // fused W1, frag-packed
    const size_t off_w2t   = alloc(E * D * D * 2);
    const size_t off_b1t   = alloc(E * D * 4);
    const size_t off_gcat  = alloc((KC * E + E) * 4);
    const size_t off_gate  = alloc(B * E * 4);
    const size_t off_acat  = alloc(B * KC * 2);
    const size_t fixedEnd = o;
    const size_t w1tBytes = E * G * D * 2;  // 33.5 MB, dead after premul

    int Eg = 1;
    {
        const int cand[4] = {8, 4, 2, 1};
        for (int c = 0; c < 4; ++c) {
            size_t h2b = 2 * (size_t)cand[c] * B * D * 2;
            size_t dyn = h2b > w1tBytes ? h2b : w1tBytes;
            if (fixedEnd + dyn <= ws_size || cand[c] == 1) { Eg = cand[c]; break; }
        }
    }

    __bf16* wbf   = (__bf16*)(ws + off_wbf);
    __bf16* w1cat = (__bf16*)(ws + off_w1cat);
    __bf16* w2t   = (__bf16*)(ws + off_w2t);
    float*  b1t   = (float*)(ws + off_b1t);
    float*  gcat  = (float*)(ws + off_gcat);
    float*  gate  = (float*)(ws + off_gate);
    __bf16* acat  = (__bf16*)(ws + off_acat);
    __bf16* w1t   = (__bf16*)(ws + fixedEnd);              // aliased: dead after premul
    __bf16* h1    = (__bf16*)(ws + fixedEnd);              // overwrites w1t in expert loop
    __bf16* h2    = h1 + (size_t)Eg * B * D;

    // 1) casts: weights (A-packed bf16) and activations (acat A-packed)
    const int nw8 = (int)(DV * D / 8);
    cast2_kernel<<<(2 * nw8 + 255) / 256, 256, 0, stream>>>(vis_w, txt_w, wbf, nw8);
    const int na8 = (int)(B * KC / 8);
    cast_acat<<<(na8 + 255) / 256, 256, 0, stream>>>(visual, text, acat, na8);

    // 2) frag-pack w1 (B input of premul) and w2
    frag_cast<<<dim3(G / 64, D / 64, E), 256, 0, stream>>>(w1, w1t, (int)G, (int)D, G * D, G * D);
    frag_cast<<<dim3(D / 64, D / 64, E), 256, 0, stream>>>(w2, w2t, (int)D, (int)D, D * D, D * D);

    // 3) weight pre-multiply: W1cat = [vis_w@w1_top ; txt_w@w1_bot], packed
    gemm_premul<<<dim3(768 / BM, D / BN, 16), 256, 0, stream>>>(wbf, w1t, w1cat);

    // 4) fused biases: b1t = b1 + bcat@w1 ; Gcat = [vis_w;txt_w]@gw (+bg~)
    hipMemsetAsync(b1t, 0, E * D * 4, stream);
    bias1_kernel<<<dim3(4, 8, 4), 256, 0, stream>>>(w1, vis_b, txt_b, b1, b1t);
    gcat_kernel<<<1537, 256, 0, stream>>>(vis_w, txt_w, vis_b, txt_b, gate_w, gate_b, gcat);

    // 5) gate softmax from packed acat
    gate_kernel<<<(int)B, 256, 0, stream>>>(acat, gcat, gate);

    // 6) experts in groups of Eg: h1 = gelu(acat@W1cat + b1t) [A-packed out];
    //    h2 = h1@w2 + b2 [row-major out]; LN+reduce
    const int ng = 8 / Eg;
    for (int g = 0; g < ng; ++g) {
        const int g0 = g * Eg;
        gemm_bt<1, 2><<<dim3(B / BM, D / BN, Eg), 256, 0, stream>>>(
            acat, (int)KC, 0, w1cat + (size_t)g0 * KC * D, (int)D, KC * D,
            b1t + (size_t)g0 * D, D, h1, (int)D, B * D);
        gemm_bt<0, 0><<<dim3(B / BM, D / BN, Eg), 256, 0, stream>>>(
            h1, (int)D, B * D, w2t + (size_t)g0 * D * D, (int)D, D * D,
            b2 + (size_t)g0 * D, D, h2, (int)D, B * D);
        ln_out_kernel<<<(int)B, 256, 0, stream>>>(h2, gate, ln_g, ln_b, out, Eg, g0, g > 0 ? 1 : 0);
    }
}

// Round 6
// 772.099 us; speedup vs baseline: 1.0833x; 1.0694x over previous
//
#include <hip/hip_runtime.h>
#include <hip/hip_bf16.h>
#include <math.h>

// Round-0 proven 128x128x64 2-barrier GEMM structure with A pre-packed in
// tile-packed layout [mblk][chunk][row][8]:
//  - global_load_lds staging fully linear/coalesced (1KB/wave/instr)
//  - LDS frag reads lane-contiguous -> 0 bank conflicts (R5 PMC: 6.29M -> 0)
//  - GEMM1 134.5us / 758 TF = m97-structure ceiling.
// NOTE: 8-phase/double-buffer schedules REGRESSED 3x (R1/R2/R4: 180/156/160us
// vs 135us) — multi-block/CU overlap beats lockstep pipelining. Do not re-add.
// R6: cast_acat/cast2 LDS-transpose (coalesced packed writes; R5 scattered
// them, +30us), gate_kernel 64-rows/block (coalesced packed reads).
#define BM 128
#define BN 128
#define BK 64

typedef __bf16 bf16x8_t __attribute__((ext_vector_type(8)));
typedef __bf16 bf16x4_t __attribute__((ext_vector_type(4)));
typedef float f32x16_t __attribute__((ext_vector_type(16)));

static __device__ __forceinline__ float bf2f(__bf16 b) {
    unsigned short s = __builtin_bit_cast(unsigned short, b);
    unsigned int u = ((unsigned int)s) << 16;
    return __builtin_bit_cast(float, u);
}
static __device__ __forceinline__ __bf16 f2bf(float f) {
    unsigned int u = __builtin_bit_cast(unsigned int, f);
    unsigned int r = (u + 0x7fffu + ((u >> 16) & 1u)) >> 16;
    return __builtin_bit_cast(__bf16, (unsigned short)r);
}
// GELU tanh-form, |err vs exact| ~1e-3 << 4e-2 tolerance.
static __device__ __forceinline__ float gelu_fast(float x) {
    const float s = x * (0.7978845608f + 0.0356774081f * x * x);
    const float e = __expf(-2.0f * s);
    return x * __builtin_amdgcn_rcpf(1.0f + e);
}

#define GLDS16(gp, lp)                                                                   \
    __builtin_amdgcn_global_load_lds((const __attribute__((address_space(1))) void*)(gp), \
                                     (__attribute__((address_space(3))) void*)(lp), 16, 0, 0)

// ---------------------------------------------------------------------------
// frag_cast: fp32 W[K][N] -> bf16 B'[K/8][N][8], B'[c][n][j] = W[c*8+j][n].
// ---------------------------------------------------------------------------
__global__ __launch_bounds__(256) void frag_cast(const float* __restrict__ in,
                                                 __bf16* __restrict__ out,
                                                 int K, int N,
                                                 size_t inStride, size_t outStride) {
    in += (size_t)blockIdx.z * inStride;
    out += (size_t)blockIdx.z * outStride;
    __shared__ float tile[64][65];
    const int k0 = blockIdx.x * 64, n0 = blockIdx.y * 64;
    const int tid = threadIdx.x;
    const int r = tid >> 4, c4 = (tid & 15) * 4;
#pragma unroll
    for (int p = 0; p < 4; ++p) {
        const float4 v = *(const float4*)&in[(size_t)(k0 + r + p * 16) * N + n0 + c4];
        tile[r + p * 16][c4 + 0] = v.x;
        tile[r + p * 16][c4 + 1] = v.y;
        tile[r + p * 16][c4 + 2] = v.z;
        tile[r + p * 16][c4 + 3] = v.w;
    }
    __syncthreads();
    const int c = tid >> 5, nn0 = (tid & 31) * 2;
#pragma unroll
    for (int t = 0; t < 2; ++t) {
        const int nn = nn0 + t;
        bf16x8_t v;
#pragma unroll
        for (int j = 0; j < 8; ++j) v[j] = f2bf(tile[c * 8 + j][nn]);
        *(bf16x8_t*)&out[((size_t)(k0 >> 3) + c) * N * 8 + (size_t)(n0 + nn) * 8] = v;
    }
}

// ---------------------------------------------------------------------------
// cast2: two fp32 [768][1024] -> bf16 A-packed [m][mblk(6)][chunk(128)][row(128)][8]
// via LDS transpose: coalesced fp32 reads AND coalesced packed writes.
// grid (16 colTiles, 6 mblks, 2 matrices), 256 threads, tile 128x64.
// ---------------------------------------------------------------------------
__global__ __launch_bounds__(256) void cast2_kernel(const float* __restrict__ a,
                                                    const float* __restrict__ b,
                                                    __bf16* __restrict__ out) {
    __shared__ __align__(16) __bf16 lds[8 * 1032];
    const int ct = blockIdx.x, mb = blockIdx.y, m = blockIdx.z, tid = threadIdx.x;
    const int c0 = ct * 64;
    const float* src = (m ? b : a) + (size_t)mb * 128 * 1024 + c0;
#pragma unroll
    for (int k = 0; k < 8; ++k) {
        const int f = tid + k * 256;
        const int row = f >> 4, c4 = f & 15;
        const float4 v = *(const float4*)(src + (size_t)row * 1024 + c4 * 4);
        __bf16* d = lds + (c4 >> 1) * 1032 + row * 8 + (c4 & 1) * 4;
        d[0] = f2bf(v.x); d[1] = f2bf(v.y); d[2] = f2bf(v.z); d[3] = f2bf(v.w);
    }
    __syncthreads();
    __bf16* dst = out + (size_t)m * 786432 + (size_t)mb * 131072 + (size_t)(c0 >> 3) * 1024;
#pragma unroll
    for (int k = 0; k < 4; ++k) {
        const int g = tid + k * 256;
        const int ch = g >> 7, row = g & 127;
        const bf16x8_t v = *(const bf16x8_t*)(lds + ch * 1032 + row * 8);
        *(bf16x8_t*)(dst + (size_t)ch * 1024 + row * 8) = v;
    }
}

// ---------------------------------------------------------------------------
// cast_acat: visual/text [8192][768] fp32 -> A-packed bf16
// acatP[mblk(64)][chunk(192)][row(128)][8], logical row = [vis | txt].
// LDS transpose; grid (24 colTiles, 64 mblks), 256 threads, tile 128x64.
// ---------------------------------------------------------------------------
__global__ __launch_bounds__(256) void cast_acat(const float* __restrict__ vis,
                                                 const float* __restrict__ txt,
                                                 __bf16* __restrict__ out) {
    __shared__ __align__(16) __bf16 lds[8 * 1032];
    const int ct = blockIdx.x, mb = blockIdx.y, tid = threadIdx.x;
    const int c0 = ct * 64;
    const float* src = (c0 < 768) ? vis + (size_t)mb * 128 * 768 + c0
                                  : txt + (size_t)mb * 128 * 768 + (c0 - 768);
#pragma unroll
    for (int k = 0; k < 8; ++k) {
        const int f = tid + k * 256;
        const int row = f >> 4, c4 = f & 15;
        const float4 v = *(const float4*)(src + (size_t)row * 768 + c4 * 4);
        __bf16* d = lds + (c4 >> 1) * 1032 + row * 8 + (c4 & 1) * 4;
        d[0] = f2bf(v.x); d[1] = f2bf(v.y); d[2] = f2bf(v.z); d[3] = f2bf(v.w);
    }
    __syncthreads();
    __bf16* dst = out + (size_t)mb * 196608 + (size_t)(c0 >> 3) * 1024;
#pragma unroll
    for (int k = 0; k < 4; ++k) {
        const int g = tid + k * 256;
        const int ch = g >> 7, row = g & 127;
        const bf16x8_t v = *(const bf16x8_t*)(lds + ch * 1032 + row * 8);
        *(bf16x8_t*)(dst + (size_t)ch * 1024 + row * 8) = v;
    }
}

#define MFMA32(a, b, c) __builtin_amdgcn_mfma_f32_32x32x16_bf16(a, b, c, 0, 0, 0)

// ---------------------------------------------------------------------------
// Core bf16 GEMM tile (round-0 schedule): C[128x128] = act(A @ W + bias).
// A in packed layout [mblk][K/8 chunks][128 rows][8]; W frag-packed
// B'[K/8][N][8] read straight to VGPRs. 2x2 waves x (2x2 mfma 32x32x16).
// PACK: 0 = row-major C; 1 = B-frag-packed C [M/8][N][8] (premul output);
//       2 = A-packed C [mblk][chunk][row][8] (feeds next GEMM's A).
// ---------------------------------------------------------------------------
template <int ACT, int PACK>
static __device__ __forceinline__ void gemm_core(const __bf16* __restrict__ A, int K,
                                                 const __bf16* __restrict__ Bt, int Bn,
                                                 const float* __restrict__ bias,
                                                 __bf16* __restrict__ C, int ldc,
                                                 int bm, int bn, __bf16* As) {
    const int tid = threadIdx.x;
    const int lane = tid & 63, wave = tid >> 6;
    const int wm = wave >> 1, wn = wave & 1;
    const int l = lane & 31, hi = lane >> 5;

    // A staging: packed source is linear -> coalesced 1KB/wave, linear dest.
    const __bf16* ag = A + (size_t)bm * K * 128 + (size_t)tid * 8;
    __bf16* asl = As + tid * 8;

    // A frag read: chunk (2s+hi)*1024 + (row wm*64 + mi*32 + l)*8; lane-contig.
    const __bf16* base_a = As + hi * 1024 + (wm * 64 + l) * 8;

    // B fragment base: frag(s,ni) at chunk kt*8+2s+hi, col bn*BN+wn*64+ni*32+l
    const size_t Bn8 = (size_t)Bn * 8;
    const __bf16* bbase = Bt + (size_t)hi * Bn8 + (size_t)(bn * BN + wn * 64 + l) * 8;
    const size_t bAdv = 8 * Bn8;

    f32x16_t acc[2][2] = {};

    const int nk = K / BK;
    for (int kt = 0; kt < nk; ++kt) {
        bf16x8_t bfr[4][2];
#pragma unroll
        for (int s = 0; s < 4; ++s) {
            bfr[s][0] = *(const bf16x8_t*)(bbase + (size_t)(2 * s) * Bn8);
            bfr[s][1] = *(const bf16x8_t*)(bbase + (size_t)(2 * s) * Bn8 + 256);
        }
        GLDS16(ag, asl);
        GLDS16(ag + 2048, asl + 2048);
        GLDS16(ag + 4096, asl + 4096);
        GLDS16(ag + 6144, asl + 6144);
        ag += 8192;
        bbase += bAdv;
        __syncthreads();
#pragma unroll
        for (int s = 0; s < 4; ++s) {
            const bf16x8_t a0 = *(const bf16x8_t*)(base_a + s * 2048);
            const bf16x8_t a1 = *(const bf16x8_t*)(base_a + s * 2048 + 256);
            acc[0][0] = MFMA32(a0, bfr[s][0], acc[0][0]);
            acc[0][1] = MFMA32(a0, bfr[s][1], acc[0][1]);
            acc[1][0] = MFMA32(a1, bfr[s][0], acc[1][0]);
            acc[1][1] = MFMA32(a1, bfr[s][1], acc[1][1]);
        }
        __syncthreads();
    }

    // epilogue: 32x32 C/D layout: col = lane&31, row = (reg&3)+8*(reg>>2)+4*hi
    const int colbase = bn * BN + wn * 64 + l;
    const int rowbase = bm * BM + wm * 64 + 4 * hi;
#pragma unroll
    for (int ni = 0; ni < 2; ++ni) {
        const int col = colbase + ni * 32;
        const float bv = (PACK == 1) ? 0.0f : bias[col];
#pragma unroll
        for (int mi = 0; mi < 2; ++mi) {
#pragma unroll
            for (int v = 0; v < 16; ++v) {
                const int row = rowbase + mi * 32 + (v & 3) + 8 * (v >> 2);
                float x = acc[mi][ni][v] + bv;
                if (ACT == 1) x = gelu_fast(x);
                if (PACK == 1) {
                    C[((size_t)(row >> 3)) * (size_t)ldc * 8 + (size_t)col * 8 + (row & 7)] = f2bf(x);
                } else if (PACK == 2) {
                    C[(size_t)(row >> 7) * (size_t)ldc * 128 + (size_t)(col >> 3) * 1024 +
                      (size_t)(row & 127) * 8 + (col & 7)] = f2bf(x);
                } else {
                    C[(size_t)row * ldc + col] = f2bf(x);
                }
            }
        }
    }
}

template <int ACT, int PACK>
__global__ __launch_bounds__(256) void gemm_bt(const __bf16* __restrict__ Ab, int K, size_t strideAe,
                                               const __bf16* __restrict__ Bb, int Bn, size_t strideBe,
                                               const float* __restrict__ biasb, size_t strideBiasE,
                                               __bf16* __restrict__ Cb, int ldc, size_t strideCe) {
    __shared__ __bf16 As[BM * BK];  // 16 KB
    gemm_core<ACT, PACK>(Ab + (size_t)blockIdx.z * strideAe, K,
                         Bb + (size_t)blockIdx.z * strideBe, Bn,
                         biasb + (size_t)blockIdx.z * strideBiasE,
                         Cb + (size_t)blockIdx.z * strideCe, ldc,
                         blockIdx.x, blockIdx.y, As);
}

// Weight pre-multiply: W1cat[e] rows [0,768) = vis_w@w1_top[e], rows [768,1536)
// = txt_w@w1_bot[e]; output frag-packed for direct use as B in w1 GEMM.
// z = e + 8*hf; M=768, N=1024, K=1024. A = packed wbf (cast2 layout).
__global__ __launch_bounds__(256) void gemm_premul(const __bf16* __restrict__ wbf,
                                                   const __bf16* __restrict__ w1t,
                                                   __bf16* __restrict__ w1cat) {
    __shared__ __bf16 As[BM * BK];
    const int e = blockIdx.z & 7, hf = blockIdx.z >> 3;
    gemm_core<0, 1>(wbf + (size_t)hf * 786432, 1024,
                    w1t + (size_t)e * 2048 * 1024 + (size_t)hf * 128 * 1024 * 8, 1024,
                    nullptr,
                    w1cat + (size_t)e * 1536 * 1024 + (size_t)hf * 96 * 1024 * 8, 1024,
                    blockIdx.x, blockIdx.y, As);
}

// ---------------------------------------------------------------------------
// b1t[e][n] = b1[e][n] + sum_d bcat[d]*w1[e][d][n], bcat=[vis_b|txt_b].
// ---------------------------------------------------------------------------
__global__ __launch_bounds__(256) void bias1_kernel(const float* __restrict__ w1,
                                                    const float* __restrict__ vis_b,
                                                    const float* __restrict__ txt_b,
                                                    const float* __restrict__ b1,
                                                    float* __restrict__ b1t) {
    const int n = blockIdx.x * 256 + threadIdx.x;
    const int e = blockIdx.y;
    const int d0 = blockIdx.z * 512;
    float acc = (blockIdx.z == 0) ? b1[(size_t)e * 1024 + n] : 0.0f;
#pragma unroll 4
    for (int d = d0; d < d0 + 512; ++d) {
        const float bv = (d < 1024) ? vis_b[d] : txt_b[d - 1024];
        acc += bv * w1[((size_t)e * 2048 + d) * 1024 + n];
    }
    atomicAdd(&b1t[(size_t)e * 1024 + n], acc);
}

// ---------------------------------------------------------------------------
// Gcat[v][j] (v<1536) = sum_d w_row[v][d]*gw[dglob][j]; block 1536 computes
// bg~[j] = sum_d bcat[d]*gw[d][j] + gate_b[j], stored at Gcat+1536*8.
// ---------------------------------------------------------------------------
__global__ __launch_bounds__(256) void gcat_kernel(const float* __restrict__ vis_w,
                                                   const float* __restrict__ txt_w,
                                                   const float* __restrict__ vis_b,
                                                   const float* __restrict__ txt_b,
                                                   const float* __restrict__ gw,
                                                   const float* __restrict__ gb,
                                                   float* __restrict__ gcat) {
    const int v = blockIdx.x, tid = threadIdx.x;
    const int lane = tid & 63, wv = tid >> 6;
    float a[8] = {0, 0, 0, 0, 0, 0, 0, 0};
    if (v < 1536) {
        const float* wr = (v < 768) ? vis_w + (size_t)v * 1024 : txt_w + (size_t)(v - 768) * 1024;
        const int dbase = (v < 768) ? 0 : 1024;
        for (int d = tid; d < 1024; d += 256) {
            const float c = wr[d];
            const float4* g4 = (const float4*)(gw + (size_t)(dbase + d) * 8);
            const float4 x = g4[0], y = g4[1];
            a[0] += c * x.x; a[1] += c * x.y; a[2] += c * x.z; a[3] += c * x.w;
            a[4] += c * y.x; a[5] += c * y.y; a[6] += c * y.z; a[7] += c * y.w;
        }
    } else {
        for (int d = tid; d < 2048; d += 256) {
            const float c = (d < 1024) ? vis_b[d] : txt_b[d - 1024];
            const float4* g4 = (const float4*)(gw + (size_t)d * 8);
            const float4 x = g4[0], y = g4[1];
            a[0] += c * x.x; a[1] += c * x.y; a[2] += c * x.z; a[3] += c * x.w;
            a[4] += c * y.x; a[5] += c * y.y; a[6] += c * y.z; a[7] += c * y.w;
        }
    }
#pragma unroll
    for (int j = 0; j < 8; ++j)
        for (int off = 32; off; off >>= 1) a[j] += __shfl_down(a[j], off, 64);
    __shared__ float red[4][8];
    if (lane == 0) {
#pragma unroll
        for (int j = 0; j < 8; ++j) red[wv][j] = a[j];
    }
    __syncthreads();
    if (tid < 8) {
        float s = red[0][tid] + red[1][tid] + red[2][tid] + red[3][tid];
        if (v == 1536) s += gb[tid];
        gcat[(size_t)v * 8 + tid] = s;
    }
}

// ---------------------------------------------------------------------------
// Gate: softmax(acat @ Gcat + bg~). 128 blocks x 64 rows; wave w reads chunks
// w+4k (coalesced packed 16B/lane), gcat addresses wave-uniform (scalarized).
// ---------------------------------------------------------------------------
__global__ __launch_bounds__(256) void gate_kernel(const __bf16* __restrict__ acat,
                                                   const float* __restrict__ gcat,
                                                   float* __restrict__ gate) {
    const int bid = blockIdx.x, tid = threadIdx.x;
    const int lane = tid & 63, wv = tid >> 6;
    const int mblk = bid >> 1;
    const int rowIn = (bid & 1) * 64 + lane;
    const __bf16* base = acat + (size_t)mblk * 196608 + (size_t)rowIn * 8;
    float a[8] = {0, 0, 0, 0, 0, 0, 0, 0};
    for (int k = 0; k < 48; ++k) {
        const int c = wv + 4 * k;
        const bf16x8_t av = *(const bf16x8_t*)(base + (size_t)c * 1024);
        const float* g = gcat + (size_t)c * 64;
#pragma unroll
        for (int jj = 0; jj < 8; ++jj) {
            const float cf = bf2f(av[jj]);
            const float4 x = *(const float4*)(g + jj * 8);
            const float4 y = *(const float4*)(g + jj * 8 + 4);
            a[0] += cf * x.x; a[1] += cf * x.y; a[2] += cf * x.z; a[3] += cf * x.w;
            a[4] += cf * y.x; a[5] += cf * y.y; a[6] += cf * y.z; a[7] += cf * y.w;
        }
    }
    __shared__ float red[4][64][9];
#pragma unroll
    for (int j = 0; j < 8; ++j) red[wv][lane][j] = a[j];
    __syncthreads();
    if (tid < 64) {
        const float* bg = gcat + 1536 * 8;
        float l[8];
        float m = -1e30f;
#pragma unroll
        for (int j = 0; j < 8; ++j) {
            l[j] = red[0][tid][j] + red[1][tid][j] + red[2][tid][j] + red[3][tid][j] + bg[j];
            m = fmaxf(m, l[j]);
        }
        float s = 0.f;
#pragma unroll
        for (int j = 0; j < 8; ++j) { l[j] = expf(l[j] - m); s += l[j]; }
        const float inv = 1.0f / s;
        const size_t r = (size_t)bid * 64 + tid;
#pragma unroll
        for (int j = 0; j < 8; ++j) gate[r * 8 + j] = l[j] * inv;
    }
}

// ---------------------------------------------------------------------------
// Fused LayerNorm + gated expert reduction (h2 row-major). One block/row.
// ---------------------------------------------------------------------------
__global__ __launch_bounds__(256) void ln_out_kernel(const __bf16* __restrict__ h2,
                                                     const float* __restrict__ gate,
                                                     const float* __restrict__ lng,
                                                     const float* __restrict__ lnb,
                                                     float* __restrict__ out,
                                                     int Eg, int g0, int accum) {
    const int b = blockIdx.x;
    const int tid = threadIdx.x;
    const int lane = tid & 63, wv = tid >> 6;
    const int d0 = tid * 4;
    __shared__ float sS[4], sSS[4];
    float* orow = out + (size_t)b * 1024 + d0;
    float o0, o1, o2, o3;
    if (accum) {
        const float4 p = *(const float4*)orow;
        o0 = p.x; o1 = p.y; o2 = p.z; o3 = p.w;
    } else {
        o0 = o1 = o2 = o3 = 0.f;
    }
    for (int e = 0; e < Eg; ++e) {
        const __bf16* hp = h2 + ((size_t)e * 8192 + b) * 1024 + d0;
        const bf16x4_t hv = *(const bf16x4_t*)hp;
        const float v0 = bf2f(hv[0]), v1 = bf2f(hv[1]), v2 = bf2f(hv[2]), v3 = bf2f(hv[3]);
        float s = v0 + v1 + v2 + v3;
        float ss = v0 * v0 + v1 * v1 + v2 * v2 + v3 * v3;
        for (int off = 32; off; off >>= 1) {
            s += __shfl_down(s, off, 64);
            ss += __shfl_down(ss, off, 64);
        }
        if (lane == 0) { sS[wv] = s; sSS[wv] = ss; }
        __syncthreads();
        const float S = sS[0] + sS[1] + sS[2] + sS[3];
        const float SS = sSS[0] + sSS[1] + sSS[2] + sSS[3];
        __syncthreads();
        const float mu = S * (1.0f / 1024.0f);
        const float var = SS * (1.0f / 1024.0f) - mu * mu;
        const float rstd = rsqrtf(var + 1e-5f);
        const float w = gate[(size_t)b * 8 + g0 + e];
        const float4 gg = *(const float4*)(lng + (size_t)(g0 + e) * 1024 + d0);
        const float4 bb = *(const float4*)(lnb + (size_t)(g0 + e) * 1024 + d0);
        o0 += w * ((v0 - mu) * rstd * gg.x + bb.x);
        o1 += w * ((v1 - mu) * rstd * gg.y + bb.y);
        o2 += w * ((v2 - mu) * rstd * gg.z + bb.z);
        o3 += w * ((v3 - mu) * rstd * gg.w + bb.w);
    }
    *(float4*)orow = make_float4(o0, o1, o2, o3);
}

// ---------------------------------------------------------------------------
extern "C" void kernel_launch(void* const* d_in, const int* in_sizes, int n_in,
                              void* d_out, int out_size, void* d_ws, size_t ws_size,
                              hipStream_t stream) {
    (void)in_sizes; (void)n_in; (void)out_size;
    const float* visual = (const float*)d_in[0];
    const float* text   = (const float*)d_in[1];
    const float* vis_w  = (const float*)d_in[2];
    const float* vis_b  = (const float*)d_in[3];
    const float* txt_w  = (const float*)d_in[4];
    const float* txt_b  = (const float*)d_in[5];
    const float* gate_w = (const float*)d_in[6];
    const float* gate_b = (const float*)d_in[7];
    const float* w1     = (const float*)d_in[8];
    const float* b1     = (const float*)d_in[9];
    const float* w2     = (const float*)d_in[10];
    const float* b2     = (const float*)d_in[11];
    const float* ln_g   = (const float*)d_in[12];
    const float* ln_b   = (const float*)d_in[13];
    float* out = (float*)d_out;

    const size_t B = 8192, DV = 768, D = 1024, G = 2048, E = 8, KC = 1536;

    char* ws = (char*)d_ws;
    size_t o = 0;
    auto alloc = [&](size_t bytes) { size_t r = o; o = (o + bytes + 255) & ~(size_t)255; return r; };
    const size_t off_wbf   = alloc(2 * DV * D * 2);        // packed vis_w | txt_w
    const size_t off_w1cat = alloc(E * KC * D * 2);        // fused W1, frag-packed
    const size_t off_w2t   = alloc(E * D * D * 2);
    const size_t off_b1t   = alloc(E * D * 4);
    const size_t off_gcat  = alloc((KC * E + E) * 4);
    const size_t off_gate  = alloc(B * E * 4);
    const size_t off_acat  = alloc(B * KC * 2);
    const size_t fixedEnd = o;
    const size_t w1tBytes = E * G * D * 2;  // 33.5 MB, dead after premul

    int Eg = 1;
    {
        const int cand[4] = {8, 4, 2, 1};
        for (int c = 0; c < 4; ++c) {
            size_t h2b = 2 * (size_t)cand[c] * B * D * 2;
            size_t dyn = h2b > w1tBytes ? h2b : w1tBytes;
            if (fixedEnd + dyn <= ws_size || cand[c] == 1) { Eg = cand[c]; break; }
        }
    }

    __bf16* wbf   = (__bf16*)(ws + off_wbf);
    __bf16* w1cat = (__bf16*)(ws + off_w1cat);
    __bf16* w2t   = (__bf16*)(ws + off_w2t);
    float*  b1t   = (float*)(ws + off_b1t);
    float*  gcat  = (float*)(ws + off_gcat);
    float*  gate  = (float*)(ws + off_gate);
    __bf16* acat  = (__bf16*)(ws + off_acat);
    __bf16* w1t   = (__bf16*)(ws + fixedEnd);              // aliased: dead after premul
    __bf16* h1    = (__bf16*)(ws + fixedEnd);              // overwrites w1t in expert loop
    __bf16* h2    = h1 + (size_t)Eg * B * D;

    // 1) casts: weights (A-packed bf16) and activations (acat A-packed)
    cast2_kernel<<<dim3(16, 6, 2), 256, 0, stream>>>(vis_w, txt_w, wbf);
    cast_acat<<<dim3(24, 64), 256, 0, stream>>>(visual, text, acat);

    // 2) frag-pack w1 (B input of premul) and w2
    frag_cast<<<dim3(G / 64, D / 64, E), 256, 0, stream>>>(w1, w1t, (int)G, (int)D, G * D, G * D);
    frag_cast<<<dim3(D / 64, D / 64, E), 256, 0, stream>>>(w2, w2t, (int)D, (int)D, D * D, D * D);

    // 3) weight pre-multiply: W1cat = [vis_w@w1_top ; txt_w@w1_bot], packed
    gemm_premul<<<dim3(768 / BM, D / BN, 16), 256, 0, stream>>>(wbf, w1t, w1cat);

    // 4) fused biases: b1t = b1 + bcat@w1 ; Gcat = [vis_w;txt_w]@gw (+bg~)
    hipMemsetAsync(b1t, 0, E * D * 4, stream);
    bias1_kernel<<<dim3(4, 8, 4), 256, 0, stream>>>(w1, vis_b, txt_b, b1, b1t);
    gcat_kernel<<<1537, 256, 0, stream>>>(vis_w, txt_w, vis_b, txt_b, gate_w, gate_b, gcat);

    // 5) gate softmax from packed acat (coalesced)
    gate_kernel<<<128, 256, 0, stream>>>(acat, gcat, gate);

    // 6) experts in groups of Eg: h1 = gelu(acat@W1cat + b1t) [A-packed out];
    //    h2 = h1@w2 + b2 [row-major out]; LN+reduce
    const int ng = 8 / Eg;
    for (int g = 0; g < ng; ++g) {
        const int g0 = g * Eg;
        gemm_bt<1, 2><<<dim3(B / BM, D / BN, Eg), 256, 0, stream>>>(
            acat, (int)KC, 0, w1cat + (size_t)g0 * KC * D, (int)D, KC * D,
            b1t + (size_t)g0 * D, D, h1, (int)D, B * D);
        gemm_bt<0, 0><<<dim3(B / BM, D / BN, Eg), 256, 0, stream>>>(
            h1, (int)D, B * D, w2t + (size_t)g0 * D * D, (int)D, D * D,
            b2 + (size_t)g0 * D, D, h2, (int)D, B * D);
        ln_out_kernel<<<(int)B, 256, 0, stream>>>(h2, gate, ln_g, ln_b, out, Eg, g0, g > 0 ? 1 : 0);
    }
}